// Round 24
// baseline (94.173 us; speedup 1.0000x reference)
//
#include <hip/hip_runtime.h>
#include <hip/hip_bf16.h>

typedef __attribute__((ext_vector_type(4))) float f32x4;
typedef __attribute__((ext_vector_type(2))) _Float16 h2;
typedef __attribute__((ext_vector_type(8))) _Float16 f16x8;

// raw workgroup barrier: waits LDS ops only (no vmcnt drain -> global prefetch
// stays in flight across the barrier)
#define LGKM_BARRIER() asm volatile("s_waitcnt lgkmcnt(0)\n\ts_barrier" ::: "memory")

// ---------------- fused weight/x transposes (r22-verified) ----------------
__global__ __launch_bounds__(256) void fused_transpose(const float* __restrict__ x,
                                                       unsigned short* __restrict__ x16h,
                                                       const float* __restrict__ dw,
                                                       unsigned short* __restrict__ wTh,
                                                       const float* __restrict__ ow,
                                                       unsigned short* __restrict__ owTh) {
    __shared__ float s[64 * 65];
    int blk = blockIdx.x;
    int tid = threadIdx.x;

    if (blk < 512) {
        int b = blk >> 8, ct = (blk >> 6) & 3, pt = blk & 63;
        int c0 = ct * 64, p0 = pt * 64;
        int tr = tid >> 6, tc = tid & 63;
#pragma unroll
        for (int i = 0; i < 16; ++i) {
            int c = i * 4 + tr;
            s[c * 65 + tc] = x[((size_t)b * 256 + c0 + c) * 4096 + p0 + tc];
        }
        __syncthreads();
#pragma unroll
        for (int i = 0; i < 16; ++i) {
            int pp = i * 4 + tr;
            _Float16 h = (_Float16)s[tc * 65 + pp];
            x16h[((size_t)b * 4096 + p0 + pp) * 256 + c0 + tc] = *(unsigned short*)&h;
        }
    } else if (blk < 1536) {
        int bb = blk - 512;               // 4 i * 256 o = 1024
        int i = bb >> 8, o = bb & 255;
        const float* src = dw + (size_t)(i * 256 + o) * 2304;
#pragma unroll
        for (int e = tid; e < 576; e += 256)
            *(float4*)&s[e * 4] = *(const float4*)&src[e * 4];
        __syncthreads();
#pragma unroll
        for (int k = 0; k < 9; ++k) {
            _Float16 h = (_Float16)s[tid * 9 + k];
            wTh[(((size_t)i * 9 + k) * 256 + o) * 256 + tid] = *(unsigned short*)&h;
        }
    } else {
        int idx = (blk - 1536) * 256 + tid;    // 294912
        int c = idx & 255;
        int m = (idx >> 8) & 31;
        int rk = idx >> 13;
        int k = rk % 9, r = rk / 9;
        float v = (m < 18) ? ow[((r * 18 + m) * 256 + c) * 9 + k] : 0.f;
        _Float16 h = (_Float16)v;
        owTh[idx] = *(unsigned short*)&h;
    }
}

// ---------------- offset conv v4 (r23-verified): 512 blocks x 256 thr ----------------
__global__ __launch_bounds__(256) void offset_mfma4f(const unsigned short* __restrict__ x16h,
                                                     const unsigned short* __restrict__ owTh,
                                                     const float* __restrict__ obias,
                                                     float* __restrict__ off) {
    __shared__ short    s_a[8][32][8];     // 4 KB  [octet][m][8ch]
    __shared__ short    s_b[8][64][8];     // 8 KB  [octet][px][8ch]
    __shared__ int      s_pix[9][64];
    __shared__ unsigned s_msk[9][64];

    const int blk = blockIdx.x;
    const int r = (blk & 7) >> 1, b = blk & 1;
    const int px0 = (blk >> 3) << 6;
    const int rate = 6 * (r + 1);

    const int tid = threadIdx.x;
    const int lane = tid & 63;
    const int w = tid >> 6;                       // wave = 16-px slice
    const int kg = lane >> 4, lm = lane & 15;
    const int pxB = tid >> 2, cgB = tid & 3;      // B staging: pixel (0..63), octet base
    const int mA = (tid & 127) >> 2, kgA = tid & 3;  // A staging (tid<128)

    const unsigned short* xbh = x16h + (size_t)b * 1048576;
    const unsigned short* wrb = owTh + (size_t)r * 9 * 32 * 256;

    for (int e = tid; e < 576; e += 256) {
        int k = e >> 6, pl = e & 63;
        int pg = px0 + pl;
        int yy = (pg >> 6) + (k / 3 - 1) * rate;
        int xx = (pg & 63) + (k % 3 - 1) * rate;
        bool v = ((unsigned)yy < 64u) && ((unsigned)xx < 64u);
        int cy = min(max(yy, 0), 63), cx = min(max(xx, 0), 63);
        s_pix[k][pl] = cy * 64 + cx;
        s_msk[k][pl] = v ? 0xFFFFFFFFu : 0u;
    }
    __syncthreads();

    f32x4 acc0 = (f32x4)(0.f), acc1 = (f32x4)(0.f);

    uint4 a_lo, a_hi, v_lo, v_hi;
    if (tid < 128) {
        a_lo = *(const uint4*)(wrb + (size_t)mA * 256 + kgA * 8);
        a_hi = *(const uint4*)(wrb + (size_t)mA * 256 + 32 + kgA * 8);
    }
    {
        int pix = s_pix[0][pxB];
        v_lo = *(const uint4*)(xbh + (size_t)pix * 256 + cgB * 8);
        v_hi = *(const uint4*)(xbh + (size_t)pix * 256 + 32 + cgB * 8);
    }
    unsigned m = s_msk[0][pxB];

    for (int t = 0; t < 36; ++t) {
        uint4 pkl = make_uint4(v_lo.x & m, v_lo.y & m, v_lo.z & m, v_lo.w & m);
        uint4 pkh = make_uint4(v_hi.x & m, v_hi.y & m, v_hi.z & m, v_hi.w & m);

        LGKM_BARRIER();
        if (tid < 128) {
            *(uint4*)&s_a[kgA][mA][0]     = a_lo;
            *(uint4*)&s_a[kgA + 4][mA][0] = a_hi;
        }
        *(uint4*)&s_b[cgB][pxB][0]     = pkl;
        *(uint4*)&s_b[cgB + 4][pxB][0] = pkh;
        LGKM_BARRIER();

        if (t < 35) {
            int tn = t + 1, tapn = tn >> 2, c0n = (tn & 3) << 6;
            if (tid < 128) {
                a_lo = *(const uint4*)(wrb + ((size_t)tapn * 32 + mA) * 256 + c0n + kgA * 8);
                a_hi = *(const uint4*)(wrb + ((size_t)tapn * 32 + mA) * 256 + c0n + 32 + kgA * 8);
            }
            int pix = s_pix[tapn][pxB];
            m = s_msk[tapn][pxB];
            v_lo = *(const uint4*)(xbh + (size_t)pix * 256 + c0n + cgB * 8);
            v_hi = *(const uint4*)(xbh + (size_t)pix * 256 + c0n + 32 + cgB * 8);
        }

#pragma unroll
        for (int kf = 0; kf < 2; ++kf) {
            int oct = kf * 4 + kg;
            f16x8 bf  = *(const f16x8*)&s_b[oct][w * 16 + lm][0];
            f16x8 af0 = *(const f16x8*)&s_a[oct][lm][0];
            f16x8 af1 = *(const f16x8*)&s_a[oct][16 + lm][0];
            acc0 = __builtin_amdgcn_mfma_f32_16x16x32_f16(af0, bf, acc0, 0, 0, 0);
            acc1 = __builtin_amdgcn_mfma_f32_16x16x32_f16(af1, bf, acc1, 0, 0, 0);
        }
    }

    const float* bias = obias + r * 18;
    float* ob = off + (size_t)(r * 2 + b) * 18 * 4096;
    int px = px0 + w * 16 + lm;
#pragma unroll
    for (int reg = 0; reg < 4; ++reg) {
        int mm = kg * 4 + reg;
        ob[(size_t)mm * 4096 + px] = fmaxf(acc0[reg] + bias[mm], 0.f);
        int m1 = 16 + mm;
        if (m1 < 18)
            ob[(size_t)m1 * 4096 + px] = fmaxf(acc1[reg] + bias[m1], 0.f);
    }
}

// ---------------- deformable conv v18: mfma9 + packed coord tables -> 3 blocks/CU ----------------
// Identical to the 68us deform_mfma9 except the coord tables are packed:
// s_pix int4(16B) -> ushort4(8B), s_wt float4(16B) -> f16x4(8B, pre-converted —
// the per-step f32->f16 conversion was happening anyway, so bitwise-identical).
// LDS 59392 -> 50176 => 3 blocks/CU (150.5KB <= 160KB; VGPR 56 <= 64 for 24 waves).
__global__ __launch_bounds__(512, 2) void deform_mfma18(const unsigned short* __restrict__ x16h,
                                                        const unsigned short* __restrict__ wTh,
                                                        const float* __restrict__ off,
                                                        float* __restrict__ out) {
    __shared__ short          s_a[256][64];   // 32 KB, col swizzle
    __shared__ short          s_b[64][64];    //  8 KB
    __shared__ unsigned short s_pix[9][64][4];// 4.5 KB (pix < 4096 fits u16)
    __shared__ unsigned short s_wt[9][64][4]; // 4.5 KB (f16 bilinear weights)

    const int blk = blockIdx.x;
    const int i = (blk & 7) >> 1, b = blk & 1;
    const int px0 = (blk >> 3) << 6;
    const int r = (i + 3) & 3;
    const int rate = 6 * (i + 1);

    const int tid = threadIdx.x;
    const int lane = tid & 63;
    const int w = tid >> 6;
    const int wo = w >> 1, wp = w & 1;
    const int kg = lane >> 4, lm = lane & 15;
    const int pxS = tid >> 3, chgS = tid & 7;
    const int oA = tid >> 3, partA = tid & 7;
    const int colA = (partA * 8) ^ ((oA & 7) * 8);

    const unsigned short* xbh = x16h + (size_t)b * 1048576;
    const float* offb = off + (size_t)(r * 2 + b) * 18 * 4096;
    const unsigned short* wib = wTh + (size_t)i * 9 * 65536;

    for (int e = tid; e < 576; e += 512) {
        int k = e >> 6, pl = e & 63;
        int pg = px0 + pl;
        int yy = pg >> 6, xc = pg & 63;
        float dy = offb[(size_t)(2 * k) * 4096 + pg];
        float dx = offb[(size_t)(2 * k + 1) * 4096 + pg];
        float py = (float)(yy + (k / 3 - 1) * rate) + dy;
        float pxf = (float)(xc + (k % 3 - 1) * rate) + dx;
        float fy = floorf(py), fx = floorf(pxf);
        int y0 = (int)fy, x0 = (int)fx;
        float wy = py - fy, wx = pxf - fx;
        float vy0 = ((unsigned)y0 < 64u) ? 1.f : 0.f;
        float vy1 = ((unsigned)(y0 + 1) < 64u) ? 1.f : 0.f;
        float vx0 = ((unsigned)x0 < 64u) ? 1.f : 0.f;
        float vx1 = ((unsigned)(x0 + 1) < 64u) ? 1.f : 0.f;
        int cy0 = min(max(y0, 0), 63), cy1 = min(max(y0 + 1, 0), 63);
        int cx0 = min(max(x0, 0), 63), cx1 = min(max(x0 + 1, 0), 63);
        s_pix[k][pl][0] = (unsigned short)(cy0 * 64 + cx0);
        s_pix[k][pl][1] = (unsigned short)(cy0 * 64 + cx1);
        s_pix[k][pl][2] = (unsigned short)(cy1 * 64 + cx0);
        s_pix[k][pl][3] = (unsigned short)(cy1 * 64 + cx1);
        _Float16 h0 = (_Float16)(vy0 * vx0 * (1.f - wy) * (1.f - wx));
        _Float16 h1 = (_Float16)(vy0 * vx1 * (1.f - wy) * wx);
        _Float16 h2v = (_Float16)(vy1 * vx0 * wy * (1.f - wx));
        _Float16 h3 = (_Float16)(vy1 * vx1 * wy * wx);
        s_wt[k][pl][0] = *(unsigned short*)&h0;
        s_wt[k][pl][1] = *(unsigned short*)&h1;
        s_wt[k][pl][2] = *(unsigned short*)&h2v;
        s_wt[k][pl][3] = *(unsigned short*)&h3;
    }
    __syncthreads();

    f32x4 acc[4][2];
#pragma unroll
    for (int mi = 0; mi < 4; ++mi) {
        acc[mi][0] = (f32x4)(0.f);
        acc[mi][1] = (f32x4)(0.f);
    }

    // prologue: issue loads for t=0
    uint4 a0, a1, a2, a3, v0, v1, v2, v3;
    {
        const unsigned short* wrow = wib + partA * 8;
        a0 = *(const uint4*)(wrow + (size_t)(oA      ) * 256);
        a1 = *(const uint4*)(wrow + (size_t)(oA +  64) * 256);
        a2 = *(const uint4*)(wrow + (size_t)(oA + 128) * 256);
        a3 = *(const uint4*)(wrow + (size_t)(oA + 192) * 256);
        ushort4 p = *(const ushort4*)&s_pix[0][pxS][0];
        const unsigned short* xch = xbh + chgS * 8;
        v0 = *(const uint4*)(xch + ((size_t)p.x << 8));
        v1 = *(const uint4*)(xch + ((size_t)p.y << 8));
        v2 = *(const uint4*)(xch + ((size_t)p.z << 8));
        v3 = *(const uint4*)(xch + ((size_t)p.w << 8));
    }

    for (int t = 0; t < 36; ++t) {
        const int tap = t >> 2;

        // lerp current step's corners (packed f16; weights pre-converted)
        uint4 pk;
        {
            unsigned short w0 = s_wt[tap][pxS][0], w1 = s_wt[tap][pxS][1];
            unsigned short w2 = s_wt[tap][pxS][2], w3 = s_wt[tap][pxS][3];
            h2 qx = (h2)(*(_Float16*)&w0), qy = (h2)(*(_Float16*)&w1);
            h2 qz = (h2)(*(_Float16*)&w2), qv = (h2)(*(_Float16*)&w3);
            h2 r0 = (*(h2*)&v0.x) * qx + (*(h2*)&v1.x) * qy + (*(h2*)&v2.x) * qz + (*(h2*)&v3.x) * qv;
            h2 r1 = (*(h2*)&v0.y) * qx + (*(h2*)&v1.y) * qy + (*(h2*)&v2.y) * qz + (*(h2*)&v3.y) * qv;
            h2 r2 = (*(h2*)&v0.z) * qx + (*(h2*)&v1.z) * qy + (*(h2*)&v2.z) * qz + (*(h2*)&v3.z) * qv;
            h2 r3 = (*(h2*)&v0.w) * qx + (*(h2*)&v1.w) * qy + (*(h2*)&v2.w) * qz + (*(h2*)&v3.w) * qv;
            pk = make_uint4(*(unsigned*)&r0, *(unsigned*)&r1, *(unsigned*)&r2, *(unsigned*)&r3);
        }

        LGKM_BARRIER();                 // prev step's LDS reads done (no vmcnt drain)
        *(uint4*)&s_a[oA      ][colA] = a0;
        *(uint4*)&s_a[oA +  64][colA] = a1;
        *(uint4*)&s_a[oA + 128][colA] = a2;
        *(uint4*)&s_a[oA + 192][colA] = a3;
        *(uint4*)&s_b[pxS][(chgS ^ (pxS & 7)) * 8] = pk;
        LGKM_BARRIER();                 // staging visible (no vmcnt drain)

        if (t < 35) {   // prefetch t+1: flies across next step's barriers
            int tn = t + 1, tapn = tn >> 2, c0n = (tn & 3) << 6;
            const unsigned short* wrow = wib + (size_t)tapn * 65536 + c0n + partA * 8;
            a0 = *(const uint4*)(wrow + (size_t)(oA      ) * 256);
            a1 = *(const uint4*)(wrow + (size_t)(oA +  64) * 256);
            a2 = *(const uint4*)(wrow + (size_t)(oA + 128) * 256);
            a3 = *(const uint4*)(wrow + (size_t)(oA + 192) * 256);
            ushort4 p = *(const ushort4*)&s_pix[tapn][pxS][0];
            const unsigned short* xch = xbh + c0n + chgS * 8;
            v0 = *(const uint4*)(xch + ((size_t)p.x << 8));
            v1 = *(const uint4*)(xch + ((size_t)p.y << 8));
            v2 = *(const uint4*)(xch + ((size_t)p.z << 8));
            v3 = *(const uint4*)(xch + ((size_t)p.w << 8));
        }

#pragma unroll
        for (int kf = 0; kf < 2; ++kf) {
            int oct = kf * 4 + kg;
            int bcol = (oct ^ (lm & 7)) * 8;
            f16x8 bf0 = *(const f16x8*)&s_b[wp * 32 + lm][bcol];
            f16x8 bf1 = *(const f16x8*)&s_b[wp * 32 + 16 + lm][bcol];
#pragma unroll
            for (int mi = 0; mi < 4; ++mi) {
                int o = wo * 64 + mi * 16 + lm;
                int col = (oct * 8) ^ ((o & 7) * 8);
                f16x8 af = *(const f16x8*)&s_a[o][col];
                acc[mi][0] = __builtin_amdgcn_mfma_f32_16x16x32_f16(af, bf0, acc[mi][0], 0, 0, 0);
                acc[mi][1] = __builtin_amdgcn_mfma_f32_16x16x32_f16(af, bf1, acc[mi][1], 0, 0, 0);
            }
        }
    }

    // epilogue: C/D col = lane&15 (px), row = kg*4 + reg (o)
    float* ob = out + ((size_t)b * 1024 + i * 256) * 4096;
#pragma unroll
    for (int mi = 0; mi < 4; ++mi) {
        int o = wo * 64 + mi * 16 + kg * 4;
#pragma unroll
        for (int ni = 0; ni < 2; ++ni) {
            int pg = px0 + wp * 32 + ni * 16 + lm;
#pragma unroll
            for (int reg = 0; reg < 4; ++reg)
                ob[(size_t)(o + reg) * 4096 + pg] = acc[mi][ni][reg];
        }
    }
}

extern "C" void kernel_launch(void* const* d_in, const int* in_sizes, int n_in,
                              void* d_out, int out_size, void* d_ws, size_t ws_size,
                              hipStream_t stream) {
    const float* x  = (const float*)d_in[0];   // [2,256,64,64]
    const float* dw = (const float*)d_in[1];   // [4,256,256,3,3]
    const float* ow = (const float*)d_in[2];   // [4,18,256,3,3]
    const float* ob = (const float*)d_in[3];   // [4,18]
    float* out = (float*)d_out;                // [2,1024,64,64]

    float* ws  = (float*)d_ws;
    float* off = ws;                                        // 589824 f32
    unsigned short* wTh  = (unsigned short*)(ws + 589824);  // 2359296 f16
    unsigned short* owTh = wTh + 2359296;                   // 294912 f16
    unsigned short* x16h = (unsigned short*)(ws + 1916928); // 2097152 f16 [b][pix][c]

    fused_transpose<<<2688, 256, 0, stream>>>(x, x16h, dw, wTh, ow, owTh);
    offset_mfma4f<<<512, 256, 0, stream>>>(x16h, owTh, ob, off);
    deform_mfma18<<<512, 512, 0, stream>>>(x16h, wTh, off, out);
}

// Round 25
// 92.890 us; speedup vs baseline: 1.0138x; 1.0138x over previous
//
#include <hip/hip_runtime.h>
#include <hip/hip_bf16.h>

typedef __attribute__((ext_vector_type(4))) float f32x4;
typedef __attribute__((ext_vector_type(2))) _Float16 h2;
typedef __attribute__((ext_vector_type(8))) _Float16 f16x8;

// raw workgroup barrier: waits LDS ops only (no vmcnt drain -> global prefetch
// stays in flight across the barrier)
#define LGKM_BARRIER() asm volatile("s_waitcnt lgkmcnt(0)\n\ts_barrier" ::: "memory")

// ---------------- fused weight/x transposes (r22-verified) ----------------
__global__ __launch_bounds__(256) void fused_transpose(const float* __restrict__ x,
                                                       unsigned short* __restrict__ x16h,
                                                       const float* __restrict__ dw,
                                                       unsigned short* __restrict__ wTh,
                                                       const float* __restrict__ ow,
                                                       unsigned short* __restrict__ owTh) {
    __shared__ float s[64 * 65];
    int blk = blockIdx.x;
    int tid = threadIdx.x;

    if (blk < 512) {
        int b = blk >> 8, ct = (blk >> 6) & 3, pt = blk & 63;
        int c0 = ct * 64, p0 = pt * 64;
        int tr = tid >> 6, tc = tid & 63;
#pragma unroll
        for (int i = 0; i < 16; ++i) {
            int c = i * 4 + tr;
            s[c * 65 + tc] = x[((size_t)b * 256 + c0 + c) * 4096 + p0 + tc];
        }
        __syncthreads();
#pragma unroll
        for (int i = 0; i < 16; ++i) {
            int pp = i * 4 + tr;
            _Float16 h = (_Float16)s[tc * 65 + pp];
            x16h[((size_t)b * 4096 + p0 + pp) * 256 + c0 + tc] = *(unsigned short*)&h;
        }
    } else if (blk < 1536) {
        int bb = blk - 512;               // 4 i * 256 o = 1024
        int i = bb >> 8, o = bb & 255;
        const float* src = dw + (size_t)(i * 256 + o) * 2304;
#pragma unroll
        for (int e = tid; e < 576; e += 256)
            *(float4*)&s[e * 4] = *(const float4*)&src[e * 4];
        __syncthreads();
#pragma unroll
        for (int k = 0; k < 9; ++k) {
            _Float16 h = (_Float16)s[tid * 9 + k];
            wTh[(((size_t)i * 9 + k) * 256 + o) * 256 + tid] = *(unsigned short*)&h;
        }
    } else {
        int idx = (blk - 1536) * 256 + tid;    // 294912
        int c = idx & 255;
        int m = (idx >> 8) & 31;
        int rk = idx >> 13;
        int k = rk % 9, r = rk / 9;
        float v = (m < 18) ? ow[((r * 18 + m) * 256 + c) * 9 + k] : 0.f;
        _Float16 h = (_Float16)v;
        owTh[idx] = *(unsigned short*)&h;
    }
}

// ---------------- offset conv v4 (r23-verified): 512 blocks x 256 thr ----------------
__global__ __launch_bounds__(256) void offset_mfma4f(const unsigned short* __restrict__ x16h,
                                                     const unsigned short* __restrict__ owTh,
                                                     const float* __restrict__ obias,
                                                     float* __restrict__ off) {
    __shared__ short    s_a[8][32][8];     // 4 KB  [octet][m][8ch]
    __shared__ short    s_b[8][64][8];     // 8 KB  [octet][px][8ch]
    __shared__ int      s_pix[9][64];
    __shared__ unsigned s_msk[9][64];

    const int blk = blockIdx.x;
    const int r = (blk & 7) >> 1, b = blk & 1;
    const int px0 = (blk >> 3) << 6;
    const int rate = 6 * (r + 1);

    const int tid = threadIdx.x;
    const int lane = tid & 63;
    const int w = tid >> 6;                       // wave = 16-px slice
    const int kg = lane >> 4, lm = lane & 15;
    const int pxB = tid >> 2, cgB = tid & 3;      // B staging: pixel (0..63), octet base
    const int mA = (tid & 127) >> 2, kgA = tid & 3;  // A staging (tid<128)

    const unsigned short* xbh = x16h + (size_t)b * 1048576;
    const unsigned short* wrb = owTh + (size_t)r * 9 * 32 * 256;

    for (int e = tid; e < 576; e += 256) {
        int k = e >> 6, pl = e & 63;
        int pg = px0 + pl;
        int yy = (pg >> 6) + (k / 3 - 1) * rate;
        int xx = (pg & 63) + (k % 3 - 1) * rate;
        bool v = ((unsigned)yy < 64u) && ((unsigned)xx < 64u);
        int cy = min(max(yy, 0), 63), cx = min(max(xx, 0), 63);
        s_pix[k][pl] = cy * 64 + cx;
        s_msk[k][pl] = v ? 0xFFFFFFFFu : 0u;
    }
    __syncthreads();

    f32x4 acc0 = (f32x4)(0.f), acc1 = (f32x4)(0.f);

    uint4 a_lo, a_hi, v_lo, v_hi;
    if (tid < 128) {
        a_lo = *(const uint4*)(wrb + (size_t)mA * 256 + kgA * 8);
        a_hi = *(const uint4*)(wrb + (size_t)mA * 256 + 32 + kgA * 8);
    }
    {
        int pix = s_pix[0][pxB];
        v_lo = *(const uint4*)(xbh + (size_t)pix * 256 + cgB * 8);
        v_hi = *(const uint4*)(xbh + (size_t)pix * 256 + 32 + cgB * 8);
    }
    unsigned m = s_msk[0][pxB];

    for (int t = 0; t < 36; ++t) {
        uint4 pkl = make_uint4(v_lo.x & m, v_lo.y & m, v_lo.z & m, v_lo.w & m);
        uint4 pkh = make_uint4(v_hi.x & m, v_hi.y & m, v_hi.z & m, v_hi.w & m);

        LGKM_BARRIER();
        if (tid < 128) {
            *(uint4*)&s_a[kgA][mA][0]     = a_lo;
            *(uint4*)&s_a[kgA + 4][mA][0] = a_hi;
        }
        *(uint4*)&s_b[cgB][pxB][0]     = pkl;
        *(uint4*)&s_b[cgB + 4][pxB][0] = pkh;
        LGKM_BARRIER();

        if (t < 35) {
            int tn = t + 1, tapn = tn >> 2, c0n = (tn & 3) << 6;
            if (tid < 128) {
                a_lo = *(const uint4*)(wrb + ((size_t)tapn * 32 + mA) * 256 + c0n + kgA * 8);
                a_hi = *(const uint4*)(wrb + ((size_t)tapn * 32 + mA) * 256 + c0n + 32 + kgA * 8);
            }
            int pix = s_pix[tapn][pxB];
            m = s_msk[tapn][pxB];
            v_lo = *(const uint4*)(xbh + (size_t)pix * 256 + c0n + cgB * 8);
            v_hi = *(const uint4*)(xbh + (size_t)pix * 256 + c0n + 32 + cgB * 8);
        }

#pragma unroll
        for (int kf = 0; kf < 2; ++kf) {
            int oct = kf * 4 + kg;
            f16x8 bf  = *(const f16x8*)&s_b[oct][w * 16 + lm][0];
            f16x8 af0 = *(const f16x8*)&s_a[oct][lm][0];
            f16x8 af1 = *(const f16x8*)&s_a[oct][16 + lm][0];
            acc0 = __builtin_amdgcn_mfma_f32_16x16x32_f16(af0, bf, acc0, 0, 0, 0);
            acc1 = __builtin_amdgcn_mfma_f32_16x16x32_f16(af1, bf, acc1, 0, 0, 0);
        }
    }

    const float* bias = obias + r * 18;
    float* ob = off + (size_t)(r * 2 + b) * 18 * 4096;
    int px = px0 + w * 16 + lm;
#pragma unroll
    for (int reg = 0; reg < 4; ++reg) {
        int mm = kg * 4 + reg;
        ob[(size_t)mm * 4096 + px] = fmaxf(acc0[reg] + bias[mm], 0.f);
        int m1 = 16 + mm;
        if (m1 < 18)
            ob[(size_t)m1 * 4096 + px] = fmaxf(acc1[reg] + bias[m1], 0.f);
    }
}

// ---------------- deformable conv v9 (r12/r21/r22/r23-verified, 68us) ----------------
__global__ __launch_bounds__(512, 2) void deform_mfma9(const unsigned short* __restrict__ x16h,
                                                       const unsigned short* __restrict__ wTh,
                                                       const float* __restrict__ off,
                                                       float* __restrict__ out) {
    __shared__ short  s_a[256][64];     // [o][64 step-ch], col ^= (o&7)*8 swizzle  32 KB
    __shared__ short  s_b[64][64];      // [px][oct^(px&7) octets of 8ch]            8 KB
    __shared__ int4   s_pix[9][64];
    __shared__ float4 s_wt[9][64];

    const int blk = blockIdx.x;
    const int i = (blk & 7) >> 1, b = blk & 1;
    const int px0 = (blk >> 3) << 6;
    const int r = (i + 3) & 3;
    const int rate = 6 * (i + 1);

    const int tid = threadIdx.x;
    const int lane = tid & 63;
    const int w = tid >> 6;
    const int wo = w >> 1, wp = w & 1;
    const int kg = lane >> 4, lm = lane & 15;
    const int pxS = tid >> 3, chgS = tid & 7;
    const int oA = tid >> 3, partA = tid & 7;
    const int colA = (partA * 8) ^ ((oA & 7) * 8);

    const unsigned short* xbh = x16h + (size_t)b * 1048576;
    const float* offb = off + (size_t)(r * 2 + b) * 18 * 4096;
    const unsigned short* wib = wTh + (size_t)i * 9 * 65536;

    for (int e = tid; e < 576; e += 512) {
        int k = e >> 6, pl = e & 63;
        int pg = px0 + pl;
        int yy = pg >> 6, xc = pg & 63;
        float dy = offb[(size_t)(2 * k) * 4096 + pg];
        float dx = offb[(size_t)(2 * k + 1) * 4096 + pg];
        float py = (float)(yy + (k / 3 - 1) * rate) + dy;
        float pxf = (float)(xc + (k % 3 - 1) * rate) + dx;
        float fy = floorf(py), fx = floorf(pxf);
        int y0 = (int)fy, x0 = (int)fx;
        float wy = py - fy, wx = pxf - fx;
        float vy0 = ((unsigned)y0 < 64u) ? 1.f : 0.f;
        float vy1 = ((unsigned)(y0 + 1) < 64u) ? 1.f : 0.f;
        float vx0 = ((unsigned)x0 < 64u) ? 1.f : 0.f;
        float vx1 = ((unsigned)(x0 + 1) < 64u) ? 1.f : 0.f;
        int cy0 = min(max(y0, 0), 63), cy1 = min(max(y0 + 1, 0), 63);
        int cx0 = min(max(x0, 0), 63), cx1 = min(max(x0 + 1, 0), 63);
        s_pix[k][pl] = make_int4(cy0 * 64 + cx0, cy0 * 64 + cx1,
                                 cy1 * 64 + cx0, cy1 * 64 + cx1);
        s_wt[k][pl] = make_float4(vy0 * vx0 * (1.f - wy) * (1.f - wx),
                                  vy0 * vx1 * (1.f - wy) * wx,
                                  vy1 * vx0 * wy * (1.f - wx),
                                  vy1 * vx1 * wy * wx);
    }
    __syncthreads();

    f32x4 acc[4][2];
#pragma unroll
    for (int mi = 0; mi < 4; ++mi) {
        acc[mi][0] = (f32x4)(0.f);
        acc[mi][1] = (f32x4)(0.f);
    }

    // prologue: issue loads for t=0
    uint4 a0, a1, a2, a3, v0, v1, v2, v3;
    {
        const unsigned short* wrow = wib + partA * 8;
        a0 = *(const uint4*)(wrow + (size_t)(oA      ) * 256);
        a1 = *(const uint4*)(wrow + (size_t)(oA +  64) * 256);
        a2 = *(const uint4*)(wrow + (size_t)(oA + 128) * 256);
        a3 = *(const uint4*)(wrow + (size_t)(oA + 192) * 256);
        int4 p = s_pix[0][pxS];
        const unsigned short* xch = xbh + chgS * 8;
        v0 = *(const uint4*)(xch + ((size_t)p.x << 8));
        v1 = *(const uint4*)(xch + ((size_t)p.y << 8));
        v2 = *(const uint4*)(xch + ((size_t)p.z << 8));
        v3 = *(const uint4*)(xch + ((size_t)p.w << 8));
    }

    for (int t = 0; t < 36; ++t) {
        const int tap = t >> 2;

        // lerp current step's corners (packed f16)
        uint4 pk;
        {
            float4 qwf = s_wt[tap][pxS];
            h2 qx = (h2)((_Float16)qwf.x), qy = (h2)((_Float16)qwf.y);
            h2 qz = (h2)((_Float16)qwf.z), qv = (h2)((_Float16)qwf.w);
            h2 r0 = (*(h2*)&v0.x) * qx + (*(h2*)&v1.x) * qy + (*(h2*)&v2.x) * qz + (*(h2*)&v3.x) * qv;
            h2 r1 = (*(h2*)&v0.y) * qx + (*(h2*)&v1.y) * qy + (*(h2*)&v2.y) * qz + (*(h2*)&v3.y) * qv;
            h2 r2 = (*(h2*)&v0.z) * qx + (*(h2*)&v1.z) * qy + (*(h2*)&v2.z) * qz + (*(h2*)&v3.z) * qv;
            h2 r3 = (*(h2*)&v0.w) * qx + (*(h2*)&v1.w) * qy + (*(h2*)&v2.w) * qz + (*(h2*)&v3.w) * qv;
            pk = make_uint4(*(unsigned*)&r0, *(unsigned*)&r1, *(unsigned*)&r2, *(unsigned*)&r3);
        }

        LGKM_BARRIER();                 // prev step's LDS reads done (no vmcnt drain)
        *(uint4*)&s_a[oA      ][colA] = a0;
        *(uint4*)&s_a[oA +  64][colA] = a1;
        *(uint4*)&s_a[oA + 128][colA] = a2;
        *(uint4*)&s_a[oA + 192][colA] = a3;
        *(uint4*)&s_b[pxS][(chgS ^ (pxS & 7)) * 8] = pk;
        LGKM_BARRIER();                 // staging visible (no vmcnt drain)

        if (t < 35) {   // prefetch t+1: flies across next step's barriers
            int tn = t + 1, tapn = tn >> 2, c0n = (tn & 3) << 6;
            const unsigned short* wrow = wib + (size_t)tapn * 65536 + c0n + partA * 8;
            a0 = *(const uint4*)(wrow + (size_t)(oA      ) * 256);
            a1 = *(const uint4*)(wrow + (size_t)(oA +  64) * 256);
            a2 = *(const uint4*)(wrow + (size_t)(oA + 128) * 256);
            a3 = *(const uint4*)(wrow + (size_t)(oA + 192) * 256);
            int4 p = s_pix[tapn][pxS];
            const unsigned short* xch = xbh + c0n + chgS * 8;
            v0 = *(const uint4*)(xch + ((size_t)p.x << 8));
            v1 = *(const uint4*)(xch + ((size_t)p.y << 8));
            v2 = *(const uint4*)(xch + ((size_t)p.z << 8));
            v3 = *(const uint4*)(xch + ((size_t)p.w << 8));
        }

#pragma unroll
        for (int kf = 0; kf < 2; ++kf) {
            int oct = kf * 4 + kg;
            int bcol = (oct ^ (lm & 7)) * 8;
            f16x8 bf0 = *(const f16x8*)&s_b[wp * 32 + lm][bcol];
            f16x8 bf1 = *(const f16x8*)&s_b[wp * 32 + 16 + lm][bcol];
#pragma unroll
            for (int mi = 0; mi < 4; ++mi) {
                int o = wo * 64 + mi * 16 + lm;
                int col = (oct * 8) ^ ((o & 7) * 8);
                f16x8 af = *(const f16x8*)&s_a[o][col];
                acc[mi][0] = __builtin_amdgcn_mfma_f32_16x16x32_f16(af, bf0, acc[mi][0], 0, 0, 0);
                acc[mi][1] = __builtin_amdgcn_mfma_f32_16x16x32_f16(af, bf1, acc[mi][1], 0, 0, 0);
            }
        }
    }

    // epilogue: C/D col = lane&15 (px), row = kg*4 + reg (o)
    float* ob = out + ((size_t)b * 1024 + i * 256) * 4096;
#pragma unroll
    for (int mi = 0; mi < 4; ++mi) {
        int o = wo * 64 + mi * 16 + kg * 4;
#pragma unroll
        for (int ni = 0; ni < 2; ++ni) {
            int pg = px0 + wp * 32 + ni * 16 + lm;
#pragma unroll
            for (int reg = 0; reg < 4; ++reg)
                ob[(size_t)(o + reg) * 4096 + pg] = acc[mi][ni][reg];
        }
    }
}

extern "C" void kernel_launch(void* const* d_in, const int* in_sizes, int n_in,
                              void* d_out, int out_size, void* d_ws, size_t ws_size,
                              hipStream_t stream) {
    const float* x  = (const float*)d_in[0];   // [2,256,64,64]
    const float* dw = (const float*)d_in[1];   // [4,256,256,3,3]
    const float* ow = (const float*)d_in[2];   // [4,18,256,3,3]
    const float* ob = (const float*)d_in[3];   // [4,18]
    float* out = (float*)d_out;                // [2,1024,64,64]

    float* ws  = (float*)d_ws;
    float* off = ws;                                        // 589824 f32
    unsigned short* wTh  = (unsigned short*)(ws + 589824);  // 2359296 f16
    unsigned short* owTh = wTh + 2359296;                   // 294912 f16
    unsigned short* x16h = (unsigned short*)(ws + 1916928); // 2097152 f16 [b][pix][c]

    fused_transpose<<<2688, 256, 0, stream>>>(x, x16h, dw, wTh, ow, owTh);
    offset_mfma4f<<<512, 256, 0, stream>>>(x16h, owTh, ob, off);
    deform_mfma9<<<512, 512, 0, stream>>>(x16h, wTh, off, out);
}